// Round 3
// baseline (225.094 us; speedup 1.0000x reference)
//
#include <hip/hip_runtime.h>

#define TAU 0.2f
#define VTH 0.3f

typedef __attribute__((ext_vector_type(4))) float f32x4;

// LIF half-scan over 4 timesteps: given carry-in cin, produce 4 spike outputs
// and carry-out s = TAU*u*(1-o) after the last step.
__device__ __forceinline__ f32x4 lif4(f32x4 v, float cin, float* cout) {
    float s = cin;
    f32x4 r;
#pragma unroll
    for (int t = 0; t < 4; ++t) {
        float u = s + v[t];
        bool spike = (u - VTH) > 0.0f;
        r[t] = spike ? 1.0f : 0.0f;
        s = spike ? 0.0f : TAU * u;
    }
    *cout = s;
    return r;
}

// x: [B, C, H, W, T] fp32, T = 8 innermost/contiguous. 8.4M float4.
// Coalesced lane<->float4 mapping (16 B/lane unit stride, load AND store).
// Pixel = (even-lane f4 [t0..3], odd-lane f4 [t4..7]); one __shfl_up stitches
// the carry. 4 independent float4 streams per thread per iteration (i,
// i+stride, i+2s, i+3s) so 4 nontemporal loads are in flight before the
// dependent scan/shuffle chain begins (ILP for HBM latency hiding).
// With grid=2048x256 and n_vec=8.4M the main loop runs exactly 4x and the
// guarded tail never executes.
__global__ __launch_bounds__(256) void LIFSpike_73864847556979_kernel(
    const f32x4* __restrict__ x, f32x4* __restrict__ out, int n_vec) {
    int tid = blockIdx.x * blockDim.x + threadIdx.x;
    int stride = gridDim.x * blockDim.x;
    bool even_lane = (threadIdx.x & 1) == 0;

    int i = tid;
    // Main body: no bounds checks, 4 streams in flight.
    for (; i + 3 * stride < n_vec; i += 4 * stride) {
        f32x4 v0 = __builtin_nontemporal_load(&x[i]);
        f32x4 v1 = __builtin_nontemporal_load(&x[i + stride]);
        f32x4 v2 = __builtin_nontemporal_load(&x[i + 2 * stride]);
        f32x4 v3 = __builtin_nontemporal_load(&x[i + 3 * stride]);

        float s0, s1, s2, s3;
        (void)lif4(v0, 0.0f, &s0);
        (void)lif4(v1, 0.0f, &s1);
        (void)lif4(v2, 0.0f, &s2);
        (void)lif4(v3, 0.0f, &s3);

        float c0 = __shfl_up(s0, 1);
        float c1 = __shfl_up(s1, 1);
        float c2 = __shfl_up(s2, 1);
        float c3 = __shfl_up(s3, 1);
        if (even_lane) { c0 = 0.0f; c1 = 0.0f; c2 = 0.0f; c3 = 0.0f; }

        float d;
        f32x4 r0 = lif4(v0, c0, &d);
        f32x4 r1 = lif4(v1, c1, &d);
        f32x4 r2 = lif4(v2, c2, &d);
        f32x4 r3 = lif4(v3, c3, &d);

        __builtin_nontemporal_store(r0, &out[i]);
        __builtin_nontemporal_store(r1, &out[i + stride]);
        __builtin_nontemporal_store(r2, &out[i + 2 * stride]);
        __builtin_nontemporal_store(r3, &out[i + 3 * stride]);
    }
    // Tail (never runs at the benchmarked shape; kept for correctness).
    for (; i < n_vec; i += stride) {
        f32x4 v = __builtin_nontemporal_load(&x[i]);
        float s;
        (void)lif4(v, 0.0f, &s);
        float c = __shfl_up(s, 1);
        if (even_lane) c = 0.0f;
        float d;
        f32x4 r = lif4(v, c, &d);
        __builtin_nontemporal_store(r, &out[i]);
    }
}

extern "C" void kernel_launch(void* const* d_in, const int* in_sizes, int n_in,
                              void* d_out, int out_size, void* d_ws, size_t ws_size,
                              hipStream_t stream) {
    const f32x4* x = (const f32x4*)d_in[0];
    f32x4* out = (f32x4*)d_out;
    int n_vec = in_sizes[0] / 4;  // total floats / 4

    int block = 256;
    long long need = ((long long)n_vec + block - 1) / block;
    int grid = (need > 2048) ? 2048 : (int)need;  // 8 blocks/CU, grid-stride

    LIFSpike_73864847556979_kernel<<<grid, block, 0, stream>>>(x, out, n_vec);
}

// Round 4
// 220.217 us; speedup vs baseline: 1.0221x; 1.0221x over previous
//
#include <hip/hip_runtime.h>

#define TAU 0.2f
#define VTH 0.3f

typedef __attribute__((ext_vector_type(4))) float f32x4;

// LIF half-scan over 4 timesteps: given carry-in cin, produce 4 spike outputs
// and carry-out s = TAU*u*(1-o) after the last step.
__device__ __forceinline__ f32x4 lif4(f32x4 v, float cin, float* cout) {
    float s = cin;
    f32x4 r;
#pragma unroll
    for (int t = 0; t < 4; ++t) {
        float u = s + v[t];
        bool spike = (u - VTH) > 0.0f;
        r[t] = spike ? 1.0f : 0.0f;
        s = spike ? 0.0f : TAU * u;
    }
    *cout = s;
    return r;
}

// x: [B, C, H, W, T] fp32, T = 8 innermost/contiguous. 8.4M float4.
// Coalesced lane<->float4 mapping (16 B/lane unit stride, load AND store).
// Pixel = (even-lane f4 [t0..3], odd-lane f4 [t4..7]); one __shfl_up stitches
// the carry. 2 independent float4 streams per thread per iteration (best
// measured ILP depth: R2=220.7 vs 4-wide R3=225.1 -- 4-wide spilled past the
// 64-VGPR occupancy cliff). __launch_bounds__(256, 8) pins 8 waves/EU
// (32 waves/CU): compiler must allocate <=64 VGPR, guaranteeing the
// occupancy the 2-wide body was designed for.
__global__ __launch_bounds__(256, 8) void LIFSpike_73864847556979_kernel(
    const f32x4* __restrict__ x, f32x4* __restrict__ out, int n_vec) {
    int tid = blockIdx.x * blockDim.x + threadIdx.x;
    int stride = gridDim.x * blockDim.x;
    bool even_lane = (threadIdx.x & 1) == 0;

    int i = tid;
    // Main body: 2 streams in flight, no bounds checks.
    for (; i + stride < n_vec; i += 2 * stride) {
        int j = i + stride;
        f32x4 va = __builtin_nontemporal_load(&x[i]);
        f32x4 vb = __builtin_nontemporal_load(&x[j]);

        float sa, sb;
        (void)lif4(va, 0.0f, &sa);
        (void)lif4(vb, 0.0f, &sb);

        float ca = __shfl_up(sa, 1);
        float cb = __shfl_up(sb, 1);
        if (even_lane) { ca = 0.0f; cb = 0.0f; }

        float d;
        f32x4 ra = lif4(va, ca, &d);
        f32x4 rb = lif4(vb, cb, &d);

        __builtin_nontemporal_store(ra, &out[i]);
        __builtin_nontemporal_store(rb, &out[j]);
    }
    // Tail (at the benchmarked shape this runs zero or one element).
    for (; i < n_vec; i += stride) {
        f32x4 v = __builtin_nontemporal_load(&x[i]);
        float s;
        (void)lif4(v, 0.0f, &s);
        float c = __shfl_up(s, 1);
        if (even_lane) c = 0.0f;
        float d;
        f32x4 r = lif4(v, c, &d);
        __builtin_nontemporal_store(r, &out[i]);
    }
}

extern "C" void kernel_launch(void* const* d_in, const int* in_sizes, int n_in,
                              void* d_out, int out_size, void* d_ws, size_t ws_size,
                              hipStream_t stream) {
    const f32x4* x = (const f32x4*)d_in[0];
    f32x4* out = (f32x4*)d_out;
    int n_vec = in_sizes[0] / 4;  // total floats / 4

    int block = 256;
    long long need = ((long long)n_vec + block - 1) / block;
    int grid = (need > 2048) ? 2048 : (int)need;  // 8 blocks/CU, grid-stride

    LIFSpike_73864847556979_kernel<<<grid, block, 0, stream>>>(x, out, n_vec);
}